// Round 1
// baseline (95.588 us; speedup 1.0000x reference)
//
#include <hip/hip_runtime.h>
#include <cmath>

// Problem constants: F=2048, HOP=N=1024, B=8, T=2^20
#define BATCH   8
#define TLEN    1048576
#define NFRM    1025                 // frames per batch row
#define MROWS   (BATCH * NFRM)       // 8200 frames total

// XOR swizzle for FFT ping-pong buffers (conflict-free, verified in R7/R8).
#define SWZ(i) ((i) ^ (((i) >> 4) & 15))

// ---------------------------------------------------------------------------
// R9: ONE WAVE PER FRAME — zero s_barriers.
//   - 128-thread block = 2 independent waves, each owns one frame and its own
//     8 KB LDS slice. Every __syncthreads() from R8 becomes
//     __builtin_amdgcn_wave_barrier() (compile-time ordering fence, 0 instrs):
//     DS ops from a single wave are processed in order by the LDS pipe.
//   - Each lane covers 2 network slots: tt in {lane, lane+64}. The verified
//     R7/R8 radix-4 Stockham network is reused verbatim with tid -> tt.
//   - Pretwiddle + pass 0 fused in registers: z[tt+h*128] (h=0..3) are exactly
//     pass-0's four inputs at slot tt. Deletes one LDS round trip (4 wr + 4 rd
//     per slot) and one fence.
//   - Ping-pong parity after fusion: pass1 za->zb, pass2 zb->za, pass3 za->zb.
//     Final radix-2 reads X==zb which ALIASES uf: all 8 float2 reads are done
//     into registers before any uf write (wave-ordered DS makes this safe).
// LDS: 2 waves x 8 KB = 16 KB/block -> ~10 blocks/CU (20 waves/CU).
// ---------------------------------------------------------------------------
__global__ __launch_bounds__(128)
void mdct_fft_kernel(const float* __restrict__ x,
                     const float* __restrict__ w,
                     float* __restrict__ out)
{
    __shared__ float2 zz[2][2][512];      // [wave][pingpong][point]
    const int wid  = threadIdx.x >> 6;
    const int lane = threadIdx.x & 63;
    float2* const za = zz[wid][0];
    float2* const zb = zz[wid][1];
    float*  const uf = (float*)zz[wid][1];   // fold buffer aliases zb

    const int r = blockIdx.x * 2 + wid;      // frame id
    const int b = r / NFRM;
    const int t = r - b * NFRM;

    const float* xb = x + b * TLEN + (t - 1) * 1024;

    // ---- fold: y[n] = w[n]*x[(t-1)*1024+n]
    //   p in [0,512):    u[p] = -( y[1535-p] + y[1536+p] )   (zero iff t==1024)
    //   p in [512,1024): u[p] =    y[p-512]  - y[1535-p]     (zero iff t==0)
#pragma unroll
    for (int sl = 0; sl < 2; ++sl) {
        const int tt = lane + sl * 64;       // network slot [0,128)
        {   // low chunk: p = tt*4
            const int p  = tt * 4;
            float4 res = {0.0f, 0.0f, 0.0f, 0.0f};
            if (t != NFRM - 1) {
                const int rb = 1532 - p;
                const int fb = 1536 + p;
                float4 xr = *(const float4*)(xb + rb);
                float4 wr = *(const float4*)(w  + rb);
                float4 xf = *(const float4*)(xb + fb);
                float4 wf = *(const float4*)(w  + fb);
                res.x = -(wr.w * xr.w + wf.x * xf.x);
                res.y = -(wr.z * xr.z + wf.y * xf.y);
                res.z = -(wr.y * xr.y + wf.z * xf.z);
                res.w = -(wr.x * xr.x + wf.w * xf.w);
            }
            *(float4*)&uf[p] = res;
        }
        {   // high chunk: p = 512 + tt*4
            const int p  = 512 + tt * 4;
            float4 res = {0.0f, 0.0f, 0.0f, 0.0f};
            if (t != 0) {
                const int rb = 1532 - p;
                const int fb = p - 512;
                float4 xr = *(const float4*)(xb + rb);
                float4 wr = *(const float4*)(w  + rb);
                float4 xf = *(const float4*)(xb + fb);
                float4 wf = *(const float4*)(w  + fb);
                res.x = wf.x * xf.x - wr.w * xr.w;
                res.y = wf.y * xf.y - wr.z * xr.z;
                res.z = wf.z * xf.z - wr.y * xr.y;
                res.w = wf.w * xf.w - wr.x * xr.x;
            }
            *(float4*)&uf[p] = res;
        }
    }
    __builtin_amdgcn_wave_barrier();

    // ---- pretwiddle + pass 0 fused in registers ----
    // z[n] = (u[2n] + i*u[1023-2n]) * cis(-pi*(4n+1)/4096), n = tt + h*128,
    // which are exactly pass-0's inputs P0..P3 at slot tt (s=1, p=tt, o=4*tt).
#pragma unroll
    for (int sl = 0; sl < 2; ++sl) {
        const int tt = lane + sl * 64;
        float px[4], py[4];
#pragma unroll
        for (int h = 0; h < 4; ++h) {
            const int n = tt + h * 128;
            float re = uf[2 * n];
            float im = uf[1023 - 2 * n];
            float a = (float)(4 * n + 1) * (1.0f / 4096.0f);
            float c = cospif(a), s = sinpif(a);
            px[h] = re * c + im * s;
            py[h] = im * c - re * s;
        }
        float ang = (float)tt * (1.0f / 256.0f);
        float c1 = cospif(ang), s1 = sinpif(ang);
        float c2 = c1 * c1 - s1 * s1, s2 = 2.0f * c1 * s1;
        float c3 = c1 * c2 - s1 * s2, s3 = s1 * c2 + c1 * s2;
        float sax = px[0] + px[2], say = py[0] + py[2];
        float sbx = px[1] + px[3], sby = py[1] + py[3];
        float dax = px[0] - px[2], day = py[0] - py[2];
        float dbx = px[1] - px[3], dby = py[1] - py[3];
        const int o = 4 * tt;
        za[SWZ(o)] = make_float2(sax + sbx, say + sby);
        float e1x = dax + dby, e1y = day - dbx;           // Da - i*Db
        za[SWZ(o + 1)] = make_float2(e1x * c1 + e1y * s1, e1y * c1 - e1x * s1);
        float e2x = sax - sbx, e2y = say - sby;
        za[SWZ(o + 2)] = make_float2(e2x * c2 + e2y * s2, e2y * c2 - e2x * s2);
        float e3x = dax - dby, e3y = day + dbx;           // Da + i*Db
        za[SWZ(o + 3)] = make_float2(e3x * c3 + e3y * s3, e3y * c3 - e3x * s3);
    }
    __builtin_amdgcn_wave_barrier();

    // ---- radix-4 Stockham passes 1..3 (verified network, tid -> tt) ----
    float2* X = za;
    float2* Y = zb;
#pragma unroll
    for (int j = 1; j < 4; ++j) {
        const int ls = 2 * j;
        const int s  = 1 << ls;
        const int mh = 256 >> ls;
#pragma unroll
        for (int sl = 0; sl < 2; ++sl) {
            const int tt = lane + sl * 64;
            const int p  = tt >> ls;
            float2 P0 = X[SWZ(tt)];
            float2 P1 = X[SWZ(tt + 128)];
            float2 P2 = X[SWZ(tt + 256)];
            float2 P3 = X[SWZ(tt + 384)];
            float ang = (float)p * (1.0f / (float)mh);   // pi units
            float c1 = cospif(ang), s1 = sinpif(ang);
            float c2 = c1 * c1 - s1 * s1, s2 = 2.0f * c1 * s1;
            float c3 = c1 * c2 - s1 * s2, s3 = s1 * c2 + c1 * s2;
            float sax = P0.x + P2.x, say = P0.y + P2.y;
            float sbx = P1.x + P3.x, sby = P1.y + P3.y;
            float dax = P0.x - P2.x, day = P0.y - P2.y;
            float dbx = P1.x - P3.x, dby = P1.y - P3.y;
            const int o = tt + 3 * s * p;
            Y[SWZ(o)] = make_float2(sax + sbx, say + sby);
            float e1x = dax + dby, e1y = day - dbx;       // Da - i*Db
            Y[SWZ(o + s)] = make_float2(e1x * c1 + e1y * s1, e1y * c1 - e1x * s1);
            float e2x = sax - sbx, e2y = say - sby;
            Y[SWZ(o + 2 * s)] = make_float2(e2x * c2 + e2y * s2, e2y * c2 - e2x * s2);
            float e3x = dax - dby, e3y = day + dbx;       // Da + i*Db
            Y[SWZ(o + 3 * s)] = make_float2(e3x * c3 + e3y * s3, e3y * c3 - e3x * s3);
        }
        float2* tmp = X; X = Y; Y = tmp;
        __builtin_amdgcn_wave_barrier();
    }
    // X == zb here (passes 1..3: za->zb->za->zb). zb aliases uf.

    // ---- final radix-2 (twiddle=1) + post-twiddle ----
    // X aliases uf: load ALL inputs to registers, then write (wave-ordered DS).
    float2 Av[4], Bv[4];
#pragma unroll
    for (int sl = 0; sl < 2; ++sl) {
        const int tt = lane + sl * 64;
#pragma unroll
        for (int hh = 0; hh < 2; ++hh) {
            const int k0 = tt + hh * 128;                // [0,256)
            Av[sl * 2 + hh] = X[SWZ(k0)];
            Bv[sl * 2 + hh] = X[SWZ(k0 + 256)];
        }
    }
    __builtin_amdgcn_wave_barrier();
#pragma unroll
    for (int sl = 0; sl < 2; ++sl) {
        const int tt = lane + sl * 64;
#pragma unroll
        for (int hh = 0; hh < 2; ++hh) {
            const int k0 = tt + hh * 128;
            const float2 A  = Av[sl * 2 + hh];
            const float2 Bq = Bv[sl * 2 + hh];
            float zr[2] = {A.x + Bq.x, A.x - Bq.x};      // Z[k0], Z[k0+256]
            float zi[2] = {A.y + Bq.y, A.y - Bq.y};
#pragma unroll
            for (int h = 0; h < 2; ++h) {
                const int k = k0 + h * 256;
                float a = (float)(4 * k + 1) * (1.0f / 4096.0f);
                float c = cospif(a), s = sinpif(a);
                float re = zr[h] * c + zi[h] * s;            // Re(Z * (c - i*s))
                float im = zi[h] * c - zr[h] * s;            // Im(Z * (c - i*s))
                uf[2 * k]        =  re * 0.04419417382415922f;   // sqrt(2/1024)
                uf[1023 - 2 * k] = -im * 0.04419417382415922f;
            }
        }
    }
    __builtin_amdgcn_wave_barrier();

    // ---- coalesced store: four float4 per lane ----
#pragma unroll
    for (int sl = 0; sl < 2; ++sl) {
        const int tt = lane + sl * 64;
        *(float4*)&out[r * 1024 + tt * 4]       = *(const float4*)&uf[tt * 4];
        *(float4*)&out[r * 1024 + 512 + tt * 4] = *(const float4*)&uf[512 + tt * 4];
    }
}

// ---------------------------------------------------------------------------
extern "C" void kernel_launch(void* const* d_in, const int* in_sizes, int n_in,
                              void* d_out, int out_size, void* d_ws, size_t ws_size,
                              hipStream_t stream) {
    const float* x = (const float*)d_in[0];   // (8, 1048576) fp32
    const float* w = (const float*)d_in[1];   // (2048,) fp32
    float* out = (float*)d_out;               // (8, 1025, 1024) fp32
    (void)d_ws; (void)ws_size;

    static_assert(MROWS % 2 == 0, "two frames per block");
    mdct_fft_kernel<<<MROWS / 2, 128, 0, stream>>>(x, w, out);
}

// Round 2
// 91.612 us; speedup vs baseline: 1.0434x; 1.0434x over previous
//
#include <hip/hip_runtime.h>
#include <cmath>

// Problem constants: F=2048, HOP=N=1024, B=8, T=2^20
#define BATCH   8
#define TLEN    1048576
#define NFRM    1025                 // frames per batch row
#define MROWS   (BATCH * NFRM)       // 8200 frames total

// XOR swizzle for FFT ping-pong buffers (conflict-free, verified in R7/R8).
#define SWZ(i) ((i) ^ (((i) >> 4) & 15))

// Rotation constants (angle-addition identities; all angles in pi units).
#define CK_1024 0.99999529380957619f   // cos(pi/1024)
#define SK_1024 0.00306795676296598f   // sin(pi/1024)
#define C8_1 0.92387953251128674f      // cos(pi/8)
#define S8_1 0.38268343236508978f      // sin(pi/8)
#define C8_2 0.70710678118654752f      // cos(pi/4)
#define S8_2 0.70710678118654752f      // sin(pi/4)
#define C8_3 0.38268343236508978f      // cos(3pi/8)
#define S8_3 0.92387953251128674f      // sin(3pi/8)

// ---------------------------------------------------------------------------
// R10: twiddle algebra — 48 cospif/sinpif pairs/lane/frame -> 2.
//   Every angle in the network is A(tt)+const or a chain off tt/256:
//     pretwiddle  n = tt+h*128:  A(n) = A(tt) + h/8          (const rotation)
//     post-tw     k = tt+hh*128+h*256: A(k) = A(tt)+(hh+2h)/8 (const rotation)
//     pass0       tt/256 = 4*A(tt) - 1/1024  (2 double-angle + const rotation)
//     pass j+1    ang -= ((tt>>2(j-1))&3)/M_j (4-way cndmask const rotation)
//   Base pair cis(pi*(4tt+1)/4096) computed ONCE per slot; kept live for the
//   post-twiddle. ~500 VALU instrs/lane/frame of ocml range-reduction deleted.
// Structure otherwise identical to R9 (1 wave/frame, 0 s_barriers, fused
// pretwiddle+pass0, zb/uf aliasing).
// ---------------------------------------------------------------------------
__global__ __launch_bounds__(128)
void mdct_fft_kernel(const float* __restrict__ x,
                     const float* __restrict__ w,
                     float* __restrict__ out)
{
    __shared__ float2 zz[2][2][512];      // [wave][pingpong][point]
    const int wid  = threadIdx.x >> 6;
    const int lane = threadIdx.x & 63;
    float2* const za = zz[wid][0];
    float2* const zb = zz[wid][1];
    float*  const uf = (float*)zz[wid][1];   // fold buffer aliases zb

    const int r = blockIdx.x * 2 + wid;      // frame id
    const int b = r / NFRM;
    const int t = r - b * NFRM;

    const float* xb = x + b * TLEN + (t - 1) * 1024;

    // ---- fold: y[n] = w[n]*x[(t-1)*1024+n]
#pragma unroll
    for (int sl = 0; sl < 2; ++sl) {
        const int tt = lane + sl * 64;       // network slot [0,128)
        {   // low chunk: p = tt*4
            const int p  = tt * 4;
            float4 res = {0.0f, 0.0f, 0.0f, 0.0f};
            if (t != NFRM - 1) {
                const int rb = 1532 - p;
                const int fb = 1536 + p;
                float4 xr = *(const float4*)(xb + rb);
                float4 wr = *(const float4*)(w  + rb);
                float4 xf = *(const float4*)(xb + fb);
                float4 wf = *(const float4*)(w  + fb);
                res.x = -(wr.w * xr.w + wf.x * xf.x);
                res.y = -(wr.z * xr.z + wf.y * xf.y);
                res.z = -(wr.y * xr.y + wf.z * xf.z);
                res.w = -(wr.x * xr.x + wf.w * xf.w);
            }
            *(float4*)&uf[p] = res;
        }
        {   // high chunk: p = 512 + tt*4
            const int p  = 512 + tt * 4;
            float4 res = {0.0f, 0.0f, 0.0f, 0.0f};
            if (t != 0) {
                const int rb = 1532 - p;
                const int fb = p - 512;
                float4 xr = *(const float4*)(xb + rb);
                float4 wr = *(const float4*)(w  + rb);
                float4 xf = *(const float4*)(xb + fb);
                float4 wf = *(const float4*)(w  + fb);
                res.x = wf.x * xf.x - wr.w * xr.w;
                res.y = wf.y * xf.y - wr.z * xr.z;
                res.z = wf.z * xf.z - wr.y * xr.y;
                res.w = wf.w * xf.w - wr.x * xr.x;
            }
            *(float4*)&uf[p] = res;
        }
    }
    __builtin_amdgcn_wave_barrier();

    float cbv[2], sbv[2];   // base pair cis(pi*(4tt+1)/4096) per slot
    float c1v[2], s1v[2];   // pass-twiddle chain state (angle ang_j) per slot

    // ---- pretwiddle + pass 0 fused in registers ----
#pragma unroll
    for (int sl = 0; sl < 2; ++sl) {
        const int tt = lane + sl * 64;
        // base pair: the ONLY transcendentals in the kernel
        const float ab = (float)(4 * tt + 1) * (1.0f / 4096.0f);
        const float cb = cospif(ab), sb = sinpif(ab);
        cbv[sl] = cb; sbv[sl] = sb;

        float px[4], py[4];
#pragma unroll
        for (int h = 0; h < 4; ++h) {
            const int n = tt + h * 128;
            float re = uf[2 * n];
            float im = uf[1023 - 2 * n];
            // (c,s) = cis(pi*(ab + h/8)) via constant rotation of base
            float c, s;
            if      (h == 0) { c = cb;                      s = sb; }
            else if (h == 1) { c = cb * C8_1 - sb * S8_1;   s = sb * C8_1 + cb * S8_1; }
            else if (h == 2) { c = cb * C8_2 - sb * S8_2;   s = sb * C8_2 + cb * S8_2; }
            else             { c = cb * C8_3 - sb * S8_3;   s = sb * C8_3 + cb * S8_3; }
            px[h] = re * c + im * s;
            py[h] = im * c - re * s;
        }
        // pass0 twiddle: ang0 = tt/256 = 4*ab - 1/1024
        const float c2b = cb * cb - sb * sb, s2b = 2.0f * cb * sb;       // 2*ab
        const float c4  = c2b * c2b - s2b * s2b, s4 = 2.0f * c2b * s2b;  // 4*ab
        const float c1  = c4 * CK_1024 + s4 * SK_1024;                   // 4*ab - 1/1024
        const float s1  = s4 * CK_1024 - c4 * SK_1024;
        c1v[sl] = c1; s1v[sl] = s1;
        const float c2 = c1 * c1 - s1 * s1, s2 = 2.0f * c1 * s1;
        const float c3 = c1 * c2 - s1 * s2, s3 = s1 * c2 + c1 * s2;

        float sax = px[0] + px[2], say = py[0] + py[2];
        float sbx = px[1] + px[3], sby = py[1] + py[3];
        float dax = px[0] - px[2], day = py[0] - py[2];
        float dbx = px[1] - px[3], dby = py[1] - py[3];
        const int o = 4 * tt;
        za[SWZ(o)] = make_float2(sax + sbx, say + sby);
        float e1x = dax + dby, e1y = day - dbx;           // Da - i*Db
        za[SWZ(o + 1)] = make_float2(e1x * c1 + e1y * s1, e1y * c1 - e1x * s1);
        float e2x = sax - sbx, e2y = say - sby;
        za[SWZ(o + 2)] = make_float2(e2x * c2 + e2y * s2, e2y * c2 - e2x * s2);
        float e3x = dax - dby, e3y = day + dbx;           // Da + i*Db
        za[SWZ(o + 3)] = make_float2(e3x * c3 + e3y * s3, e3y * c3 - e3x * s3);
    }
    __builtin_amdgcn_wave_barrier();

    // ---- radix-4 Stockham passes 1..3 (verified network; chained twiddles) ----
    float2* X = za;
    float2* Y = zb;
#pragma unroll
    for (int j = 1; j < 4; ++j) {
        const int ls = 2 * j;
        const int s  = 1 << ls;
#pragma unroll
        for (int sl = 0; sl < 2; ++sl) {
            const int tt = lane + sl * 64;
            const int p  = tt >> ls;
            float2 P0 = X[SWZ(tt)];
            float2 P1 = X[SWZ(tt + 128)];
            float2 P2 = X[SWZ(tt + 256)];
            float2 P3 = X[SWZ(tt + 384)];
            // chain: ang_j = ang_{j-1} - q/M_j, q = (tt>>(2j-2))&3
            const int q = (tt >> (2 * j - 2)) & 3;
            float cd, sd;
            if (j == 1) {        // M=256
                cd = q == 0 ? 1.0f : q == 1 ? 0.99992470183914450f
                   : q == 2 ? 0.99969881869620422f : 0.99932238458834954f;
                sd = q == 0 ? 0.0f : q == 1 ? 0.01227153828571993f
                   : q == 2 ? 0.02454122852291229f : 0.03680722294135883f;
            } else if (j == 2) { // M=64
                cd = q == 0 ? 1.0f : q == 1 ? 0.99879545620517241f
                   : q == 2 ? 0.99518472667219693f : 0.98917650996478101f;
                sd = q == 0 ? 0.0f : q == 1 ? 0.04906767432741802f
                   : q == 2 ? 0.09801714032956060f : 0.14673047445536175f;
            } else {             // M=16
                cd = q == 0 ? 1.0f : q == 1 ? 0.98078528040323044f
                   : q == 2 ? 0.92387953251128674f : 0.83146961230254524f;
                sd = q == 0 ? 0.0f : q == 1 ? 0.19509032201612825f
                   : q == 2 ? 0.38268343236508978f : 0.55557023301960222f;
            }
            const float c1 = c1v[sl] * cd + s1v[sl] * sd;   // ang -= d
            const float s1 = s1v[sl] * cd - c1v[sl] * sd;
            c1v[sl] = c1; s1v[sl] = s1;
            const float c2 = c1 * c1 - s1 * s1, s2 = 2.0f * c1 * s1;
            const float c3 = c1 * c2 - s1 * s2, s3 = s1 * c2 + c1 * s2;

            float sax = P0.x + P2.x, say = P0.y + P2.y;
            float sbx = P1.x + P3.x, sby = P1.y + P3.y;
            float dax = P0.x - P2.x, day = P0.y - P2.y;
            float dbx = P1.x - P3.x, dby = P1.y - P3.y;
            const int o = tt + 3 * s * p;
            Y[SWZ(o)] = make_float2(sax + sbx, say + sby);
            float e1x = dax + dby, e1y = day - dbx;       // Da - i*Db
            Y[SWZ(o + s)] = make_float2(e1x * c1 + e1y * s1, e1y * c1 - e1x * s1);
            float e2x = sax - sbx, e2y = say - sby;
            Y[SWZ(o + 2 * s)] = make_float2(e2x * c2 + e2y * s2, e2y * c2 - e2x * s2);
            float e3x = dax - dby, e3y = day + dbx;       // Da + i*Db
            Y[SWZ(o + 3 * s)] = make_float2(e3x * c3 + e3y * s3, e3y * c3 - e3x * s3);
        }
        float2* tmp = X; X = Y; Y = tmp;
        __builtin_amdgcn_wave_barrier();
    }
    // X == zb here (passes 1..3: za->zb->za->zb). zb aliases uf.

    // ---- final radix-2 (twiddle=1) + post-twiddle ----
    // X aliases uf: load ALL inputs to registers, then write (wave-ordered DS).
    float2 Av[4], Bv[4];
#pragma unroll
    for (int sl = 0; sl < 2; ++sl) {
        const int tt = lane + sl * 64;
#pragma unroll
        for (int hh = 0; hh < 2; ++hh) {
            const int k0 = tt + hh * 128;                // [0,256)
            Av[sl * 2 + hh] = X[SWZ(k0)];
            Bv[sl * 2 + hh] = X[SWZ(k0 + 256)];
        }
    }
    __builtin_amdgcn_wave_barrier();
#pragma unroll
    for (int sl = 0; sl < 2; ++sl) {
        const int tt = lane + sl * 64;
        const float cb = cbv[sl], sb = sbv[sl];
#pragma unroll
        for (int hh = 0; hh < 2; ++hh) {
            const int k0 = tt + hh * 128;
            const float2 A  = Av[sl * 2 + hh];
            const float2 Bq = Bv[sl * 2 + hh];
            float zr[2] = {A.x + Bq.x, A.x - Bq.x};      // Z[k0], Z[k0+256]
            float zi[2] = {A.y + Bq.y, A.y - Bq.y};
#pragma unroll
            for (int h = 0; h < 2; ++h) {
                const int k = k0 + h * 256;
                // A(k) = ab + (hh + 2h)/8: constant rotation of base pair
                const int idx = hh + 2 * h;
                float c, s;
                if      (idx == 0) { c = cb;                      s = sb; }
                else if (idx == 1) { c = cb * C8_1 - sb * S8_1;   s = sb * C8_1 + cb * S8_1; }
                else if (idx == 2) { c = cb * C8_2 - sb * S8_2;   s = sb * C8_2 + cb * S8_2; }
                else               { c = cb * C8_3 - sb * S8_3;   s = sb * C8_3 + cb * S8_3; }
                float re = zr[h] * c + zi[h] * s;            // Re(Z * (c - i*s))
                float im = zi[h] * c - zr[h] * s;            // Im(Z * (c - i*s))
                uf[2 * k]        =  re * 0.04419417382415922f;   // sqrt(2/1024)
                uf[1023 - 2 * k] = -im * 0.04419417382415922f;
            }
        }
    }
    __builtin_amdgcn_wave_barrier();

    // ---- coalesced store: four float4 per lane ----
#pragma unroll
    for (int sl = 0; sl < 2; ++sl) {
        const int tt = lane + sl * 64;
        *(float4*)&out[r * 1024 + tt * 4]       = *(const float4*)&uf[tt * 4];
        *(float4*)&out[r * 1024 + 512 + tt * 4] = *(const float4*)&uf[512 + tt * 4];
    }
}

// ---------------------------------------------------------------------------
extern "C" void kernel_launch(void* const* d_in, const int* in_sizes, int n_in,
                              void* d_out, int out_size, void* d_ws, size_t ws_size,
                              hipStream_t stream) {
    const float* x = (const float*)d_in[0];   // (8, 1048576) fp32
    const float* w = (const float*)d_in[1];   // (2048,) fp32
    float* out = (float*)d_out;               // (8, 1025, 1024) fp32
    (void)d_ws; (void)ws_size;

    static_assert(MROWS % 2 == 0, "two frames per block");
    mdct_fft_kernel<<<MROWS / 2, 128, 0, stream>>>(x, w, out);
}

// Round 3
// 91.133 us; speedup vs baseline: 1.0489x; 1.0053x over previous
//
#include <hip/hip_runtime.h>
#include <cmath>

// Problem constants: F=2048, HOP=N=1024, B=8, T=2^20
#define BATCH   8
#define TLEN    1048576
#define NFRM    1025                 // frames per batch row
#define MROWS   (BATCH * NFRM)       // 8200 frames total

// XOR swizzle for FFT buffer (conflict-free, verified R7-R10).
#define SWZ(i) ((i) ^ (((i) >> 4) & 15))

// Rotation constants (angle-addition identities; all angles in pi units).
#define CK_1024 0.99999529380957619f   // cos(pi/1024)
#define SK_1024 0.00306795676296598f   // sin(pi/1024)
#define C8_1 0.92387953251128674f      // cos(pi/8)
#define S8_1 0.38268343236508978f      // sin(pi/8)
#define C8_2 0.70710678118654752f      // cos(pi/4)
#define S8_2 0.70710678118654752f      // sin(pi/4)
#define C8_3 0.38268343236508978f      // cos(3pi/8)
#define S8_3 0.92387953251128674f      // sin(3pi/8)

#define OUT_SCALE 0.04419417382415922f // sqrt(2/1024)

// ---------------------------------------------------------------------------
// R11: in-place FFT + direct global stores. (R10 twiddle algebra kept as-is.)
//   - ONE 4 KB buffer per wave (was 8 KB ping-pong): with one wave per frame,
//     DS instructions are wave-wide and program-ordered, so a pass is safe
//     in-place iff ALL its reads are issued before ANY write. Each phase is
//     restructured read-all(both slots)->regs, fence, compute+write-all.
//     Every pass reads all of [0,512) and writes a bijection of [0,512).
//   - Final radix-2 + post-twiddle stores STRAIGHT to global (deletes 16
//     bank-conflicted scalar LDS writes + 4 b128 reads + the store loop).
//     The even/odd stride-2 streams from one wave land within a few dozen
//     cycles -> L2 merges to full lines; HBM write bytes unchanged.
//   - LDS 8 KB/block; __launch_bounds__(128,6) caps VGPR (~85) so occupancy
//     is ~24 waves/CU (VGPR was the binding limit, not LDS).
// ---------------------------------------------------------------------------
__global__ __launch_bounds__(128, 6)
void mdct_fft_kernel(const float* __restrict__ x,
                     const float* __restrict__ w,
                     float* __restrict__ out)
{
    __shared__ float2 zz[2][512];        // one in-place buffer per wave
    const int wid  = threadIdx.x >> 6;
    const int lane = threadIdx.x & 63;
    float2* const za = zz[wid];
    float*  const uf = (float*)zz[wid];  // fold view of the same buffer

    const int r = blockIdx.x * 2 + wid;  // frame id
    const int b = r / NFRM;
    const int t = r - b * NFRM;

    const float* xb = x + b * TLEN + (t - 1) * 1024;

    // ---- fold: y[n] = w[n]*x[(t-1)*1024+n]
    //   p in [0,512):    u[p] = -( y[1535-p] + y[1536+p] )   (zero iff t==1024)
    //   p in [512,1024): u[p] =    y[p-512]  - y[1535-p]     (zero iff t==0)
#pragma unroll
    for (int sl = 0; sl < 2; ++sl) {
        const int tt = lane + sl * 64;   // network slot [0,128)
        {   // low chunk: p = tt*4
            const int p  = tt * 4;
            float4 res = {0.0f, 0.0f, 0.0f, 0.0f};
            if (t != NFRM - 1) {
                const int rb = 1532 - p;
                const int fb = 1536 + p;
                float4 xr = *(const float4*)(xb + rb);
                float4 wr = *(const float4*)(w  + rb);
                float4 xf = *(const float4*)(xb + fb);
                float4 wf = *(const float4*)(w  + fb);
                res.x = -(wr.w * xr.w + wf.x * xf.x);
                res.y = -(wr.z * xr.z + wf.y * xf.y);
                res.z = -(wr.y * xr.y + wf.z * xf.z);
                res.w = -(wr.x * xr.x + wf.w * xf.w);
            }
            *(float4*)&uf[p] = res;
        }
        {   // high chunk: p = 512 + tt*4
            const int p  = 512 + tt * 4;
            float4 res = {0.0f, 0.0f, 0.0f, 0.0f};
            if (t != 0) {
                const int rb = 1532 - p;
                const int fb = p - 512;
                float4 xr = *(const float4*)(xb + rb);
                float4 wr = *(const float4*)(w  + rb);
                float4 xf = *(const float4*)(xb + fb);
                float4 wf = *(const float4*)(w  + fb);
                res.x = wf.x * xf.x - wr.w * xr.w;
                res.y = wf.y * xf.y - wr.z * xr.z;
                res.z = wf.z * xf.z - wr.y * xr.y;
                res.w = wf.w * xf.w - wr.x * xr.x;
            }
            *(float4*)&uf[p] = res;
        }
    }
    __builtin_amdgcn_wave_barrier();

    float cbv[2], sbv[2];   // base pair cis(pi*(4tt+1)/4096) per slot
    float c1v[2], s1v[2];   // pass-twiddle chain state per slot

    // ---- pretwiddle + pass 0, in-place: READ ALL u, fence, then write ----
    float ure[2][4], uim[2][4];
#pragma unroll
    for (int sl = 0; sl < 2; ++sl) {
        const int tt = lane + sl * 64;
#pragma unroll
        for (int h = 0; h < 4; ++h) {
            const int n = tt + h * 128;
            ure[sl][h] = uf[2 * n];
            uim[sl][h] = uf[1023 - 2 * n];
        }
    }
    __builtin_amdgcn_wave_barrier();
#pragma unroll
    for (int sl = 0; sl < 2; ++sl) {
        const int tt = lane + sl * 64;
        // base pair: the ONLY transcendentals in the kernel
        const float ab = (float)(4 * tt + 1) * (1.0f / 4096.0f);
        const float cb = cospif(ab), sb = sinpif(ab);
        cbv[sl] = cb; sbv[sl] = sb;

        float px[4], py[4];
#pragma unroll
        for (int h = 0; h < 4; ++h) {
            // (c,s) = cis(pi*(ab + h/8)) via constant rotation of base
            float c, s;
            if      (h == 0) { c = cb;                      s = sb; }
            else if (h == 1) { c = cb * C8_1 - sb * S8_1;   s = sb * C8_1 + cb * S8_1; }
            else if (h == 2) { c = cb * C8_2 - sb * S8_2;   s = sb * C8_2 + cb * S8_2; }
            else             { c = cb * C8_3 - sb * S8_3;   s = sb * C8_3 + cb * S8_3; }
            px[h] = ure[sl][h] * c + uim[sl][h] * s;
            py[h] = uim[sl][h] * c - ure[sl][h] * s;
        }
        // pass0 twiddle: ang0 = tt/256 = 4*ab - 1/1024
        const float c2b = cb * cb - sb * sb, s2b = 2.0f * cb * sb;       // 2*ab
        const float c4  = c2b * c2b - s2b * s2b, s4 = 2.0f * c2b * s2b;  // 4*ab
        const float c1  = c4 * CK_1024 + s4 * SK_1024;                   // 4*ab - 1/1024
        const float s1  = s4 * CK_1024 - c4 * SK_1024;
        c1v[sl] = c1; s1v[sl] = s1;
        const float c2 = c1 * c1 - s1 * s1, s2 = 2.0f * c1 * s1;
        const float c3 = c1 * c2 - s1 * s2, s3 = s1 * c2 + c1 * s2;

        float sax = px[0] + px[2], say = py[0] + py[2];
        float sbx = px[1] + px[3], sby = py[1] + py[3];
        float dax = px[0] - px[2], day = py[0] - py[2];
        float dbx = px[1] - px[3], dby = py[1] - py[3];
        const int o = 4 * tt;
        za[SWZ(o)] = make_float2(sax + sbx, say + sby);
        float e1x = dax + dby, e1y = day - dbx;           // Da - i*Db
        za[SWZ(o + 1)] = make_float2(e1x * c1 + e1y * s1, e1y * c1 - e1x * s1);
        float e2x = sax - sbx, e2y = say - sby;
        za[SWZ(o + 2)] = make_float2(e2x * c2 + e2y * s2, e2y * c2 - e2x * s2);
        float e3x = dax - dby, e3y = day + dbx;           // Da + i*Db
        za[SWZ(o + 3)] = make_float2(e3x * c3 + e3y * s3, e3y * c3 - e3x * s3);
    }
    __builtin_amdgcn_wave_barrier();

    // ---- radix-4 Stockham passes 1..3, in-place (read-all then write-all) --
#pragma unroll
    for (int j = 1; j < 4; ++j) {
        const int ls = 2 * j;
        const int s  = 1 << ls;
        float2 P[2][4];
#pragma unroll
        for (int sl = 0; sl < 2; ++sl) {
            const int tt = lane + sl * 64;
#pragma unroll
            for (int i = 0; i < 4; ++i)
                P[sl][i] = za[SWZ(tt + i * 128)];
        }
        __builtin_amdgcn_wave_barrier();
#pragma unroll
        for (int sl = 0; sl < 2; ++sl) {
            const int tt = lane + sl * 64;
            const int p  = tt >> ls;
            // chain: ang_j = ang_{j-1} - q/M_j, q = (tt>>(2j-2))&3
            const int q = (tt >> (2 * j - 2)) & 3;
            float cd, sd;
            if (j == 1) {        // M=256
                cd = q == 0 ? 1.0f : q == 1 ? 0.99992470183914450f
                   : q == 2 ? 0.99969881869620422f : 0.99932238458834954f;
                sd = q == 0 ? 0.0f : q == 1 ? 0.01227153828571993f
                   : q == 2 ? 0.02454122852291229f : 0.03680722294135883f;
            } else if (j == 2) { // M=64
                cd = q == 0 ? 1.0f : q == 1 ? 0.99879545620517241f
                   : q == 2 ? 0.99518472667219693f : 0.98917650996478101f;
                sd = q == 0 ? 0.0f : q == 1 ? 0.04906767432741802f
                   : q == 2 ? 0.09801714032956060f : 0.14673047445536175f;
            } else {             // M=16
                cd = q == 0 ? 1.0f : q == 1 ? 0.98078528040323044f
                   : q == 2 ? 0.92387953251128674f : 0.83146961230254524f;
                sd = q == 0 ? 0.0f : q == 1 ? 0.19509032201612825f
                   : q == 2 ? 0.38268343236508978f : 0.55557023301960222f;
            }
            const float c1 = c1v[sl] * cd + s1v[sl] * sd;   // ang -= d
            const float s1 = s1v[sl] * cd - c1v[sl] * sd;
            c1v[sl] = c1; s1v[sl] = s1;
            const float c2 = c1 * c1 - s1 * s1, s2 = 2.0f * c1 * s1;
            const float c3 = c1 * c2 - s1 * s2, s3 = s1 * c2 + c1 * s2;

            float sax = P[sl][0].x + P[sl][2].x, say = P[sl][0].y + P[sl][2].y;
            float sbx = P[sl][1].x + P[sl][3].x, sby = P[sl][1].y + P[sl][3].y;
            float dax = P[sl][0].x - P[sl][2].x, day = P[sl][0].y - P[sl][2].y;
            float dbx = P[sl][1].x - P[sl][3].x, dby = P[sl][1].y - P[sl][3].y;
            const int o = tt + 3 * s * p;
            za[SWZ(o)] = make_float2(sax + sbx, say + sby);
            float e1x = dax + dby, e1y = day - dbx;       // Da - i*Db
            za[SWZ(o + s)] = make_float2(e1x * c1 + e1y * s1, e1y * c1 - e1x * s1);
            float e2x = sax - sbx, e2y = say - sby;
            za[SWZ(o + 2 * s)] = make_float2(e2x * c2 + e2y * s2, e2y * c2 - e2x * s2);
            float e3x = dax - dby, e3y = day + dbx;       // Da + i*Db
            za[SWZ(o + 3 * s)] = make_float2(e3x * c3 + e3y * s3, e3y * c3 - e3x * s3);
        }
        __builtin_amdgcn_wave_barrier();
    }

    // ---- final radix-2 (twiddle=1) + post-twiddle + DIRECT global store ----
    // Reads only (no LDS writes): no in-place hazard.
    float* const ob = out + r * 1024;
#pragma unroll
    for (int sl = 0; sl < 2; ++sl) {
        const int tt = lane + sl * 64;
        const float cb = cbv[sl], sb = sbv[sl];
#pragma unroll
        for (int hh = 0; hh < 2; ++hh) {
            const int k0 = tt + hh * 128;                // [0,256)
            const float2 A  = za[SWZ(k0)];
            const float2 Bq = za[SWZ(k0 + 256)];
            float zr[2] = {A.x + Bq.x, A.x - Bq.x};      // Z[k0], Z[k0+256]
            float zi[2] = {A.y + Bq.y, A.y - Bq.y};
#pragma unroll
            for (int h = 0; h < 2; ++h) {
                const int k = k0 + h * 256;
                // A(k) = ab + (hh + 2h)/8: constant rotation of base pair
                const int idx = hh + 2 * h;
                float c, s;
                if      (idx == 0) { c = cb;                      s = sb; }
                else if (idx == 1) { c = cb * C8_1 - sb * S8_1;   s = sb * C8_1 + cb * S8_1; }
                else if (idx == 2) { c = cb * C8_2 - sb * S8_2;   s = sb * C8_2 + cb * S8_2; }
                else               { c = cb * C8_3 - sb * S8_3;   s = sb * C8_3 + cb * S8_3; }
                float re = zr[h] * c + zi[h] * s;            // Re(Z * (c - i*s))
                float im = zi[h] * c - zr[h] * s;            // Im(Z * (c - i*s))
                ob[2 * k]        =  re * OUT_SCALE;
                ob[1023 - 2 * k] = -im * OUT_SCALE;
            }
        }
    }
}

// ---------------------------------------------------------------------------
extern "C" void kernel_launch(void* const* d_in, const int* in_sizes, int n_in,
                              void* d_out, int out_size, void* d_ws, size_t ws_size,
                              hipStream_t stream) {
    const float* x = (const float*)d_in[0];   // (8, 1048576) fp32
    const float* w = (const float*)d_in[1];   // (2048,) fp32
    float* out = (float*)d_out;               // (8, 1025, 1024) fp32
    (void)d_ws; (void)ws_size;

    static_assert(MROWS % 2 == 0, "two frames per block");
    mdct_fft_kernel<<<MROWS / 2, 128, 0, stream>>>(x, w, out);
}